// Round 5
// baseline (108.312 us; speedup 1.0000x reference)
//
#include <hip/hip_runtime.h>

// Problem constants
#define IN_DIM   512
#define OUT_DIM  512
#define KDEG     3
#define BATCH    256
#define NB       19                 // spline basis count per input dim
#define NG       23                 // grid points per input dim
#define KAUG     20                 // 19 spline slots + 1 base(silu) slot
#define KTOT     (IN_DIM * KAUG)    // 10240
#define NKB_TOT  (KTOT / 32)        // 320 k-blocks of 32

typedef short  bf16x8 __attribute__((ext_vector_type(8)));   // 8 bf16 = 4 VGPRs
typedef float  f32x4  __attribute__((ext_vector_type(4)));

// round-to-nearest-even fp32 -> bf16
__device__ __forceinline__ unsigned short f2bf(float f) {
    union { float f; unsigned int u; } v; v.f = f;
    unsigned int r = (v.u + 0x7FFF + ((v.u >> 16) & 1)) >> 16;
    return (unsigned short)r;
}

// ---------------------------------------------------------------------------
// Fragment-major A layout (MFMA 16x16x32 A-operand order):
//   element (b, k) lives at  Af[((m_blk*320 + k_blk)*64 + quad*16 + lr)*8 + j]
//   with m_blk=b>>4, lr=b&15, k_blk=k>>5, quad=(k&31)>>3, j=k&7.
// A wave's bf16x8 fragment load is then 64 lanes x 16B fully contiguous.
// ---------------------------------------------------------------------------

// ---------------------------------------------------------------------------
// Kernel 1: build augmented A in fragment-major order.
//   A[b][i*20+g] = Bspline_g(x[b,i]),  A[b][i*20+19] = silu(x[b,i])
// Block = (i_chunk of 32 i's, m_blk of 16 b's), 256 threads, 2 cells/thread.
// Scatter bf16 into a 20KB LDS tile, then coalesced 16B dump to global.
// ---------------------------------------------------------------------------
__global__ __launch_bounds__(256) void build_A_frag(const float* __restrict__ X,
                                                    const float* __restrict__ G,
                                                    unsigned short* __restrict__ Af) {
    __shared__ __align__(16) unsigned short tile[32 * KAUG * 16];  // 20 k_blks*512 = 10240

    int t     = threadIdx.x;
    int i0    = blockIdx.x * 32;
    int m_blk = blockIdx.y;
    int lr    = t & 15;
    int b     = m_blk * 16 + lr;

#pragma unroll
    for (int r = 0; r < 2; r++) {
        int il = (t >> 4) + (r << 4);      // 0..31
        int i  = i0 + il;
        float x = X[b * IN_DIM + i];

        float gr[NG];
        const float* g = G + i * NG;
#pragma unroll
        for (int j = 0; j < NG; j++) gr[j] = g[j];

        float B[NG - 1];
#pragma unroll
        for (int j = 0; j < NG - 1; j++)
            B[j] = (x >= gr[j] && x < gr[j + 1]) ? 1.0f : 0.0f;

#pragma unroll
        for (int kk = 1; kk <= KDEG; kk++) {
#pragma unroll
            for (int j = 0; j < NG - 1 - kk; j++) {
                float d1 = gr[j + kk] - gr[j];
                float d2 = gr[j + kk + 1] - gr[j + 1];
                B[j] = (x - gr[j]) / d1 * B[j] +
                       (gr[j + kk + 1] - x) / d2 * B[j + 1];
            }
        }

        unsigned short v[KAUG];
#pragma unroll
        for (int j = 0; j < NB; j++) v[j] = f2bf(B[j]);
        v[NB] = f2bf(x / (1.0f + __expf(-x)));   // silu

        // scatter into fragment-major LDS tile (one-time, bank-benign)
#pragma unroll
        for (int gidx = 0; gidx < KAUG; gidx++) {
            int kl = il * KAUG + gidx;     // 0..639 (local k)
            tile[((kl >> 5) * 64 + ((kl & 31) >> 3) * 16 + lr) * 8 + (kl & 7)] = v[gidx];
        }
    }
    __syncthreads();

    // coalesced dump: 10240 ushorts = 1280 x 16B, 256 threads x 5
    const f32x4* src = (const f32x4*)tile;
    f32x4* dst = (f32x4*)(Af + ((size_t)m_blk * NKB_TOT + blockIdx.x * 20) * 512);
#pragma unroll
    for (int r = 0; r < 5; r++) dst[t + r * 256] = src[t + r * 256];
}

// ---------------------------------------------------------------------------
// Kernel 2: fused W-build + split-K MFMA GEMM -> fp32 partials.
//   P[z][b][o] = sum_{k in chunk z} A[b][k] * W[k][o]
//   W[(i*20+g)][o] = coef[i][o][g]*scale[i][o]*mask[i][o];  W[i*20+19][o]=mask
// Grid = (8 o-blocks[BN=64], 2 m-blocks[BM=128], 32 z[ICH=16]) = 512 blocks,
// 256 threads = 4 waves (wave owns 2 m_blks = 32 rows).
// Fill: 8 chunks x {coalesced float4 coef->raw LDS; transform -> frag-major
// B tile in LDS}. K-loop: coalesced global A-frags + ds_read_b128 B-frags,
// 8 MFMA per k-block, no barriers. LDS 50.7KB -> 3 blocks/CU.
// ---------------------------------------------------------------------------
#define BN     64
#define BM     128
#define SPLITS 32
#define ICH    16
#define NKB    10                   // k_blks per split (ICH*20/32)

__global__ __launch_bounds__(256, 3) void gemm_fused(
        const unsigned short* __restrict__ Af,
        const float* __restrict__ coef,
        const float* __restrict__ scale_sp,
        const float* __restrict__ mask,
        float* __restrict__ P) {
    __shared__ __align__(16) unsigned short Bf[4 * NKB * 512];   // 40960 B
    __shared__ __align__(16) float raw[2 * 64 * NB];             // 9728 B

    int t  = threadIdx.x;
    int o0 = blockIdx.x * BN;
    int y  = blockIdx.y;
    int z  = blockIdx.z;
    int i0 = z * ICH;

    // ---- fill phase: 8 chunks of 2 i-rows --------------------------------
    for (int c = 0; c < 8; c++) {
        int ib = 2 * c;
        // stage 2 x 304 float4 (16B-aligned, coalesced)
#pragma unroll
        for (int seg = 0; seg < 2; seg++) {
            const f32x4* gs = (const f32x4*)(coef +
                ((size_t)(i0 + ib + seg) * OUT_DIM + o0) * NB);
            f32x4* rs = (f32x4*)&raw[seg * 64 * NB];
            for (int idx = t; idx < 304; idx += 256) rs[idx] = gs[idx];
        }
        __syncthreads();

        if (t < 128) {
            int seg   = t >> 6;
            int o_loc = t & 63;
            int i_loc = ib + seg;
            int io = (i0 + i_loc) * OUT_DIM + (o0 + o_loc);
            float m  = mask[io];
            float sm = scale_sp[io] * m;
            const float* cr = &raw[seg * 64 * NB + o_loc * NB];
            int o_blk = o_loc >> 4;
            int lro   = o_loc & 15;
            int kb0   = i_loc * KAUG;      // 0..300
#pragma unroll
            for (int g = 0; g < KAUG; g++) {
                float val = (g < NB) ? cr[g] * sm : m;
                int kl = kb0 + g;
                Bf[((o_blk * NKB + (kl >> 5)) * 64 + ((kl & 31) >> 3) * 16 + lro) * 8
                   + (kl & 7)] = f2bf(val);
            }
        }
        __syncthreads();   // protects raw before next chunk; last one gates K-loop
    }

    // ---- compute phase: barrier-free unrolled K-loop ----------------------
    int lane = t & 63;
    int w    = t >> 6;                 // wave 0..3
    int quad = lane >> 4;
    int lr   = lane & 15;

    f32x4 acc[2][4];
#pragma unroll
    for (int i = 0; i < 2; i++)
#pragma unroll
        for (int j = 0; j < 4; j++) acc[i][j] = (f32x4)0.0f;

    int mb0 = y * 8 + w * 2;           // this wave's first m_blk
    const unsigned short* A0 = Af + (((size_t)(mb0 + 0) * NKB_TOT + z * NKB) * 64 + lane) * 8;
    const unsigned short* A1 = Af + (((size_t)(mb0 + 1) * NKB_TOT + z * NKB) * 64 + lane) * 8;

#pragma unroll
    for (int kb = 0; kb < NKB; kb++) {
        bf16x8 a0 = *(const bf16x8*)(A0 + (size_t)kb * 512);
        bf16x8 a1 = *(const bf16x8*)(A1 + (size_t)kb * 512);
#pragma unroll
        for (int nt = 0; nt < 4; nt++) {
            bf16x8 bfr = *(const bf16x8*)&Bf[((nt * NKB + kb) * 64 + lane) * 8];
            acc[0][nt] = __builtin_amdgcn_mfma_f32_16x16x32_bf16(a0, bfr, acc[0][nt], 0, 0, 0);
            acc[1][nt] = __builtin_amdgcn_mfma_f32_16x16x32_bf16(a1, bfr, acc[1][nt], 0, 0, 0);
        }
    }

    // ---- epilogue: C/D layout col=lane&15, row=quad*4+reg -----------------
    float* Pz = P + (size_t)z * BATCH * OUT_DIM;
#pragma unroll
    for (int mt = 0; mt < 2; mt++) {
        int bb = (mb0 + mt) * 16 + quad * 4;
#pragma unroll
        for (int nt = 0; nt < 4; nt++) {
            int col = o0 + nt * 16 + lr;
#pragma unroll
            for (int r = 0; r < 4; r++)
                Pz[(size_t)(bb + r) * OUT_DIM + col] = acc[mt][nt][r];
        }
    }
}

// ---------------------------------------------------------------------------
// Kernel 3: reduce partials: out[e] = sum_z P[z][e], float4-vectorized.
// ---------------------------------------------------------------------------
__global__ __launch_bounds__(256) void reduce_out(const float* __restrict__ P,
                                                  float* __restrict__ out) {
    int e4 = blockIdx.x * blockDim.x + threadIdx.x;   // 0 .. 32767
    f32x4 s = (f32x4)0.0f;
#pragma unroll
    for (int zz = 0; zz < SPLITS; zz++) {
        f32x4 v = *(const f32x4*)(P + (size_t)zz * BATCH * OUT_DIM + e4 * 4);
        s += v;
    }
    *(f32x4*)((float*)out + (size_t)e4 * 4) = s;
}

// ---------------------------------------------------------------------------
extern "C" void kernel_launch(void* const* d_in, const int* in_sizes, int n_in,
                              void* d_out, int out_size, void* d_ws, size_t ws_size,
                              hipStream_t stream) {
    const float* x        = (const float*)d_in[0];   // (256, 512)
    const float* grid     = (const float*)d_in[1];   // (512, 23)
    const float* coef     = (const float*)d_in[2];   // (512, 512, 19)
    const float* scale_sp = (const float*)d_in[3];   // (512, 512)
    const float* mask     = (const float*)d_in[4];   // (512, 512)
    float* out = (float*)d_out;                      // (256, 512)

    unsigned short* Af = (unsigned short*)d_ws;                   // 5.24 MB
    float* P = (float*)((char*)d_ws + (size_t)BATCH * KTOT * 2);  // 16.8 MB

    build_A_frag<<<dim3(16, 16), dim3(256), 0, stream>>>(x, grid, Af);

    gemm_fused<<<dim3(OUT_DIM / BN, BATCH / BM, SPLITS), dim3(256), 0, stream>>>(
        Af, coef, scale_sp, mask, P);

    reduce_out<<<dim3(BATCH * OUT_DIM / 4 / 256), dim3(256), 0, stream>>>(P, out);
}

// Round 6
// 99.961 us; speedup vs baseline: 1.0835x; 1.0835x over previous
//
#include <hip/hip_runtime.h>

// Problem constants
#define IN_DIM   512
#define OUT_DIM  512
#define KDEG     3
#define BATCH    256
#define NB       19                 // spline basis count per input dim
#define NG       23                 // grid points per input dim
#define KAUG     20                 // 19 spline slots + 1 base(silu) slot
#define KTOT     (IN_DIM * KAUG)    // 10240

typedef short  bf16x8 __attribute__((ext_vector_type(8)));   // 8 bf16 = 4 VGPRs
typedef float  f32x4  __attribute__((ext_vector_type(4)));

// round-to-nearest-even fp32 -> bf16
__device__ __forceinline__ unsigned short f2bf(float f) {
    union { float f; unsigned int u; } v; v.f = f;
    unsigned int r = (v.u + 0x7FFF + ((v.u >> 16) & 1)) >> 16;
    return (unsigned short)r;
}

// ---------------------------------------------------------------------------
// Kernel 1: augmented A (BATCH x KTOT), bf16, k-contiguous.  (R4 version)
//   A[b][i*20+g] = Bspline_g(x[b,i]),  A[b][i*20+19] = silu(x[b,i])
// ---------------------------------------------------------------------------
__global__ void build_A(const float* __restrict__ X,
                        const float* __restrict__ G,
                        unsigned short* __restrict__ A) {
    int t = blockIdx.x * blockDim.x + threadIdx.x;
    if (t >= BATCH * IN_DIM) return;
    int b = t / IN_DIM;
    int i = t - b * IN_DIM;

    float x = X[t];

    float gr[NG];
    const float* g = G + i * NG;
#pragma unroll
    for (int j = 0; j < NG; j++) gr[j] = g[j];

    float B[NG - 1];
#pragma unroll
    for (int j = 0; j < NG - 1; j++)
        B[j] = (x >= gr[j] && x < gr[j + 1]) ? 1.0f : 0.0f;

#pragma unroll
    for (int kk = 1; kk <= KDEG; kk++) {
#pragma unroll
        for (int j = 0; j < NG - 1 - kk; j++) {
            float d1 = gr[j + kk] - gr[j];
            float d2 = gr[j + kk + 1] - gr[j + 1];
            B[j] = (x - gr[j]) / d1 * B[j] +
                   (gr[j + kk + 1] - x) / d2 * B[j + 1];
        }
    }

    unsigned short v[KAUG];
#pragma unroll
    for (int j = 0; j < NB; j++) v[j] = f2bf(B[j]);
    v[NB] = f2bf(x / (1.0f + __expf(-x)));   // silu

    unsigned int* dst = (unsigned int*)(A + (size_t)b * KTOT + i * KAUG);
    const unsigned int* src = (const unsigned int*)v;
#pragma unroll
    for (int d = 0; d < KAUG / 2; d++) dst[d] = src[d];
}

// ---------------------------------------------------------------------------
// Kernel 2 (fused W-build + split-K GEMM -> fp32 partials).  R4 structure;
// ONLY the fill phase changed: coalesced float4 coef loads + LDS sm-table.
// Grid = (16 o-blocks, 1, 32 k-splits) = 512 blocks, 512 threads = 8 waves;
// BM=256 (wave w owns rows [32w,32w+32)), BN=32, ICH=16 -> KCH=320.
// ---------------------------------------------------------------------------
#define BN     32
#define SPLITS 32
#define ICH    16                  // i's per block
#define KCH    (ICH * KAUG)        // 320
#define LDS_K  (KCH + 8)           // 328 elems -> row stride 656B

__global__ __launch_bounds__(512, 4) void gemm_fused(
        const unsigned short* __restrict__ A,
        const float* __restrict__ coef,
        const float* __restrict__ scale_sp,
        const float* __restrict__ mask,
        float* __restrict__ P) {
    __shared__ __align__(16) unsigned short Bs[BN * LDS_K];   // 20992 B
    __shared__ float smt[ICH * 32];                           // 2048 B

    int tid = threadIdx.x;
    int o0 = blockIdx.x * BN;
    int i0 = blockIdx.z * ICH;
    int kbase = blockIdx.z * KCH;

    // ---- fill pass 1: scale*mask table + silu-slot weights (coalesced) ----
    {
        int o  = tid & 31;         // lanes sweep o
        int di = tid >> 5;         // 0..15
        int io = (i0 + di) * OUT_DIM + (o0 + o);
        float m  = mask[io];
        float sm = scale_sp[io] * m;
        smt[di * 32 + o] = sm;
        Bs[o * LDS_K + di * KAUG + NB] = f2bf(m);   // silu-slot weight
    }
    __syncthreads();

    // ---- fill pass 2: coalesced coef -> Bs --------------------------------
    // Slice coef[(i0+di)*512 + o0 .. o0+32][0..19) is 608 contiguous floats
    // = 152 16B-aligned float4 per di; 16*152 = 2432 float4, 5 rounds of 512.
    for (int p = tid; p < ICH * 152; p += 512) {
        int di  = p / 152;
        int rem = p - di * 152;
        f32x4 v = *(const f32x4*)(coef
              + ((size_t)(i0 + di) * OUT_DIM + o0) * NB + rem * 4);
#pragma unroll
        for (int e = 0; e < 4; e++) {
            int l = rem * 4 + e;          // 0..607
            int o_loc = l / 19;
            int g = l - o_loc * 19;
            // consecutive lanes -> consecutive 2B addrs: 2-way aliasing, free
            Bs[o_loc * LDS_K + di * KAUG + g] = f2bf(v[e] * smt[di * 32 + o_loc]);
        }
    }
    __syncthreads();

    // ---- compute phase: barrier-free unrolled K-loop (identical to R4) ----
    int lane = tid & 63;
    int w    = tid >> 6;           // wave 0..7, owns m-strip [32w, 32w+32)
    int quad = lane >> 4;
    int lr   = lane & 15;

    f32x4 acc[2][2];
#pragma unroll
    for (int i = 0; i < 2; i++)
#pragma unroll
        for (int j = 0; j < 2; j++) acc[i][j] = (f32x4)0.0f;

    const unsigned short* a0 = A + (size_t)(w * 32 + lr)      * KTOT + kbase + quad * 8;
    const unsigned short* a1 = A + (size_t)(w * 32 + 16 + lr) * KTOT + kbase + quad * 8;
    const unsigned short* b0 = &Bs[(size_t)lr        * LDS_K + quad * 8];
    const unsigned short* b1 = &Bs[(size_t)(16 + lr) * LDS_K + quad * 8];

#pragma unroll
    for (int kk = 0; kk < KCH; kk += 32) {
        bf16x8 af0 = *(const bf16x8*)(a0 + kk);
        bf16x8 af1 = *(const bf16x8*)(a1 + kk);
        bf16x8 bf0 = *(const bf16x8*)(b0 + kk);
        bf16x8 bf1 = *(const bf16x8*)(b1 + kk);
        acc[0][0] = __builtin_amdgcn_mfma_f32_16x16x32_bf16(af0, bf0, acc[0][0], 0, 0, 0);
        acc[0][1] = __builtin_amdgcn_mfma_f32_16x16x32_bf16(af0, bf1, acc[0][1], 0, 0, 0);
        acc[1][0] = __builtin_amdgcn_mfma_f32_16x16x32_bf16(af1, bf0, acc[1][0], 0, 0, 0);
        acc[1][1] = __builtin_amdgcn_mfma_f32_16x16x32_bf16(af1, bf1, acc[1][1], 0, 0, 0);
    }

    // ---- epilogue: plain coalesced stores into per-split partial buffer ---
    // C/D layout: col=lane&15, row=quad*4+reg
    float* Pz = P + (size_t)blockIdx.z * BATCH * OUT_DIM;
#pragma unroll
    for (int mt = 0; mt < 2; mt++) {
#pragma unroll
        for (int nt = 0; nt < 2; nt++) {
            int col = o0 + nt * 16 + lr;
            int rb  = w * 32 + mt * 16 + quad * 4;
#pragma unroll
            for (int r = 0; r < 4; r++)
                Pz[(size_t)(rb + r) * OUT_DIM + col] = acc[mt][nt][r];
        }
    }
}

// ---------------------------------------------------------------------------
// Kernel 3: reduce partials: out[e] = sum_z P[z][e], float4-vectorized.
// ---------------------------------------------------------------------------
__global__ __launch_bounds__(256) void reduce_out(const float* __restrict__ P,
                                                  float* __restrict__ out) {
    int e4 = blockIdx.x * blockDim.x + threadIdx.x;   // 0 .. 32767
    f32x4 s = (f32x4)0.0f;
#pragma unroll
    for (int zz = 0; zz < SPLITS; zz++) {
        f32x4 v = *(const f32x4*)(P + (size_t)zz * BATCH * OUT_DIM + e4 * 4);
        s += v;
    }
    *(f32x4*)((float*)out + (size_t)e4 * 4) = s;
}

// ---------------------------------------------------------------------------
extern "C" void kernel_launch(void* const* d_in, const int* in_sizes, int n_in,
                              void* d_out, int out_size, void* d_ws, size_t ws_size,
                              hipStream_t stream) {
    const float* x        = (const float*)d_in[0];   // (256, 512)
    const float* grid     = (const float*)d_in[1];   // (512, 23)
    const float* coef     = (const float*)d_in[2];   // (512, 512, 19)
    const float* scale_sp = (const float*)d_in[3];   // (512, 512)
    const float* mask     = (const float*)d_in[4];   // (512, 512)
    float* out = (float*)d_out;                      // (256, 512)

    unsigned short* A = (unsigned short*)d_ws;                        // 5.24 MB
    float* P = (float*)((char*)d_ws + (size_t)BATCH * KTOT * 2);      // 16.8 MB

    build_A<<<dim3((BATCH * IN_DIM + 255) / 256), dim3(256), 0, stream>>>(x, grid, A);

    gemm_fused<<<dim3(OUT_DIM / BN, 1, SPLITS), dim3(512), 0, stream>>>(
        A, coef, scale_sp, mask, P);

    reduce_out<<<dim3(BATCH * OUT_DIM / 4 / 256), dim3(256), 0, stream>>>(P, out);
}